// Round 9
// baseline (533.589 us; speedup 1.0000x reference)
//
#include <hip/hip_runtime.h>
#include <math.h>

#define VOCABN 100
#define EMBEDN 50
#define HID 30
#define NB 512
#define NT 512
#define G4 120  // 4*HID

__device__ __forceinline__ float fastrcp(float x) {
  float r;
  asm("v_rcp_f32 %0, %1" : "=v"(r) : "v"(x));
  return r;
}
__device__ __forceinline__ float tanh_fast(float x) {
  return 1.0f - 2.0f * fastrcp(1.0f + __expf(2.0f * x));
}
// v_permlane32_swap(x,x): lo_all = value from lanes[0..31] into all lanes,
// hi_all = value from lanes[32..63]. VALU pipe (~8cyc).
__device__ __forceinline__ void bcast_halves(float x, float& lo_all, float& hi_all) {
  auto r = __builtin_amdgcn_permlane32_swap(__builtin_bit_cast(unsigned, x),
                                            __builtin_bit_cast(unsigned, x), false, false);
  lo_all = __builtin_bit_cast(float, (unsigned)r[0]);
  hi_all = __builtin_bit_cast(float, (unsigned)r[1]);
}
__device__ __forceinline__ float rdlane(float v, int k) {
  return __builtin_bit_cast(float, __builtin_amdgcn_readlane(__builtin_bit_cast(int, v), k));
}

// ---------------- prep: xpe[tok][g] = emb[tok]@w_ih1^T + b_ih1 + b_hh1 ; b2s = b_ih2+b_hh2
// also outc[v] = lb2[v] + relu(lb1) . lw2[v]  (output row for masked timesteps)
__global__ void prep_kernel(const float* __restrict__ emb,
                            const float* __restrict__ w_ih1,
                            const float* __restrict__ b_ih1,
                            const float* __restrict__ b_hh1,
                            const float* __restrict__ b_ih2,
                            const float* __restrict__ b_hh2,
                            const float* __restrict__ lw2,
                            const float* __restrict__ lb1,
                            const float* __restrict__ lb2,
                            float* __restrict__ xpe, float* __restrict__ b2s,
                            float* __restrict__ outc) {
  __shared__ float e[EMBEDN];
  int r = blockIdx.x;
  int tid = threadIdx.x;
  if (tid < EMBEDN) e[tid] = emb[r * EMBEDN + tid];
  __syncthreads();
  if (tid < G4) {
    float s = b_ih1[tid] + b_hh1[tid];
#pragma unroll
    for (int k = 0; k < EMBEDN; ++k) s = fmaf(e[k], w_ih1[tid * EMBEDN + k], s);
    xpe[r * G4 + tid] = s;
    if (r == 0) b2s[tid] = b_ih2[tid] + b_hh2[tid];
  }
  if (r == 0 && tid < VOCABN) {
    float o = lb2[tid];
#pragma unroll
    for (int k = 0; k < HID; ++k) o = fmaf(fmaxf(lb1[k], 0.f), lw2[tid * HID + k], o);
    outc[tid] = o;
  }
}

// ---------------- scan: ONE wave per sequence. No barriers, no LDS.
// Recurrent state h1,h2 in SGPRs (readlane); all 6 weight rows register-resident
// (180 VGPR). Layer2 lags layer1 by one step inside the same wave: iteration t
// computes h1[t] (critical chain) AND h2[t-1] (filler, hides nonlin/readlane
// latency). h2 store + xpe prefetch are async, never waited on in-loop.
__global__ void __launch_bounds__(64)
__attribute__((amdgpu_waves_per_eu(1, 1)))
scan_kernel(const int* __restrict__ batch_x, const int* __restrict__ lens,
            const float* __restrict__ xpe, const float* __restrict__ b2s,
            const float* __restrict__ w_hh1, const float* __restrict__ w_ih2,
            const float* __restrict__ w_hh2, float* __restrict__ h2g) {
  const int b = blockIdx.x;
  const int lane = threadIdx.x;
  const int half = lane >> 5;
  const int j = lane & 31;
  const int jj = (j < HID) ? j : (HID - 1);
  // half0 lane j: gates (i_j, f_j); half1 lane j: gates (g_j, o_j)
  const int gA = half ? (jj + 2 * HID) : jj;
  const int gB = half ? (jj + 3 * HID) : (jj + HID);
  const float bg = half ? 2.0f : 1.0f;  // beta: 1 -> sigmoid, 2 -> tanh

  // register-resident weight rows (6 x 30 = 180 VGPR)
  float w1A[HID], w1B[HID], wiA[HID], wiB[HID], whA[HID], whB[HID];
#pragma unroll
  for (int k = 0; k < HID; ++k) {
    w1A[k] = w_hh1[gA * HID + k];
    w1B[k] = w_hh1[gB * HID + k];
    wiA[k] = w_ih2[gA * HID + k];
    wiB[k] = w_ih2[gB * HID + k];
    whA[k] = w_hh2[gA * HID + k];
    whB[k] = w_hh2[gB * HID + k];
  }
  const float b2A = b2s[gA], b2B = b2s[gB];
  const int len = lens[b];
  const int* xrow = batch_x + b * NT;  // uniform -> scalar loads

  float hs1[HID], hs2[HID];  // uniform state (SGPRs via readlane)
#pragma unroll
  for (int k = 0; k < HID; ++k) { hs1[k] = 0.f; hs2[k] = 0.f; }
  float c1 = 0.f, c2 = 0.f;

  // ---- prologue: h1[0] = nonlin(xpe[tok0])   (states all zero)
  {
    int tok0 = xrow[0];
    float a0 = xpe[tok0 * G4 + gA];
    float a1 = xpe[tok0 * G4 + gB];
    float sA = 1.0f - bg * fastrcp(1.0f + __expf(bg * a0));
    float sB = 1.0f - fastrcp(1.0f + __expf(a1));
    float i1, g1, f1, o1;
    bcast_halves(sA, i1, g1);
    bcast_halves(sB, f1, o1);
    (void)f1;
    c1 = i1 * g1;
    float h1n = o1 * tanh_fast(c1);
#pragma unroll
    for (int k = 0; k < HID; ++k) hs1[k] = rdlane(h1n, k);
  }

  // xpe prefetch pipeline: xaC/xbC for iteration t, xaN/xbN for t+1
  int tk1 = xrow[(1 < NT) ? 1 : 0];
  float xaC = xpe[tk1 * G4 + gA];
  float xbC = xpe[tk1 * G4 + gB];
  int tk2 = xrow[(2 < NT) ? 2 : (NT - 1)];
  float xaN = xpe[tk2 * G4 + gA];
  float xbN = xpe[tk2 * G4 + gB];

  for (int t = 1; t < len; ++t) {
    // ---- L1 dot (critical): gates1 = w_hh1 . h1[t-1] + xpe[tok t]
    float a0a = 0.f, a0b = 0.f, a1a = 0.f, a1b = 0.f;
#pragma unroll
    for (int p = 0; p < 15; ++p) {
      a0a = fmaf(hs1[p], w1A[p], a0a);
      a1a = fmaf(hs1[p], w1B[p], a1a);
      a0b = fmaf(hs1[p + 15], w1A[p + 15], a0b);
      a1b = fmaf(hs1[p + 15], w1B[p + 15], a1b);
    }
    // ---- L2 dots (filler): gates2 = w_ih2 . h1[t-1] + w_hh2 . h2[t-2] + b2
    float q0a = 0.f, q0b = 0.f, q1a = 0.f, q1b = 0.f;
#pragma unroll
    for (int p = 0; p < 15; ++p) {
      q0a = fmaf(hs1[p], wiA[p], q0a);
      q1a = fmaf(hs1[p], wiB[p], q1a);
      q0b = fmaf(hs1[p + 15], wiA[p + 15], q0b);
      q1b = fmaf(hs1[p + 15], wiB[p + 15], q1b);
    }
#pragma unroll
    for (int p = 0; p < 15; ++p) {
      q0a = fmaf(hs2[p], whA[p], q0a);
      q1a = fmaf(hs2[p], whB[p], q1a);
      q0b = fmaf(hs2[p + 15], whA[p + 15], q0b);
      q1b = fmaf(hs2[p + 15], whB[p + 15], q1b);
    }

    // ---- L1 nonlin -> h1[t]
    float a0 = a0a + a0b + xaC;
    float a1 = a1a + a1b + xbC;
    float sA = 1.0f - bg * fastrcp(1.0f + __expf(bg * a0));
    float sB = 1.0f - fastrcp(1.0f + __expf(a1));
    float i1, g1, f1, o1;
    bcast_halves(sA, i1, g1);
    bcast_halves(sB, f1, o1);
    c1 = fmaf(f1, c1, i1 * g1);
    float h1n = o1 * tanh_fast(c1);

    // ---- L2 nonlin -> h2[t-1]
    float q0 = q0a + q0b + b2A;
    float q1 = q1a + q1b + b2B;
    float uA = 1.0f - bg * fastrcp(1.0f + __expf(bg * q0));
    float uB = 1.0f - fastrcp(1.0f + __expf(q1));
    float i2, g2, f2, o2;
    bcast_halves(uA, i2, g2);
    bcast_halves(uB, f2, o2);
    c2 = fmaf(f2, c2, i2 * g2);
    float h2n = o2 * tanh_fast(c2);

    // ---- async store h2[t-1]
    if (lane < HID) h2g[((size_t)(t - 1) * NB + b) * HID + lane] = h2n;

    // ---- state update (SGPRs); independent readlanes overlap with next prefetch
#pragma unroll
    for (int k = 0; k < HID; ++k) hs1[k] = rdlane(h1n, k);
#pragma unroll
    for (int k = 0; k < HID; ++k) hs2[k] = rdlane(h2n, k);

    // ---- rotate xpe prefetch (2-step slack)
    xaC = xaN;
    xbC = xbN;
    int tn = t + 2;
    int tkn = xrow[(tn < NT) ? tn : (NT - 1)];
    xaN = xpe[tkn * G4 + gA];
    xbN = xpe[tkn * G4 + gB];
  }

  // ---- epilogue: h2[len-1] from h1[len-1], h2[len-2]
  {
    float q0a = 0.f, q0b = 0.f, q1a = 0.f, q1b = 0.f;
#pragma unroll
    for (int p = 0; p < 15; ++p) {
      q0a = fmaf(hs1[p], wiA[p], q0a);
      q1a = fmaf(hs1[p], wiB[p], q1a);
      q0b = fmaf(hs1[p + 15], wiA[p + 15], q0b);
      q1b = fmaf(hs1[p + 15], wiB[p + 15], q1b);
    }
#pragma unroll
    for (int p = 0; p < 15; ++p) {
      q0a = fmaf(hs2[p], whA[p], q0a);
      q1a = fmaf(hs2[p], whB[p], q1a);
      q0b = fmaf(hs2[p + 15], whA[p + 15], q0b);
      q1b = fmaf(hs2[p + 15], whB[p + 15], q1b);
    }
    float q0 = q0a + q0b + b2A;
    float q1 = q1a + q1b + b2B;
    float uA = 1.0f - bg * fastrcp(1.0f + __expf(bg * q0));
    float uB = 1.0f - fastrcp(1.0f + __expf(q1));
    float i2, g2, f2, o2;
    bcast_halves(uA, i2, g2);
    bcast_halves(uB, f2, o2);
    c2 = fmaf(f2, c2, i2 * g2);
    float h2n = o2 * tanh_fast(c2);
    if (lane < HID) h2g[((size_t)(len - 1) * NB + b) * HID + lane] = h2n;
  }
}

// ---------------- head MLP: no LDS. Per-lane hoisted weights; hmid broadcast
// via readlane->SGPR; next-row global prefetch; 2-row ping-pong.
__global__ void __launch_bounds__(256)
__attribute__((amdgpu_waves_per_eu(1, 2)))
final_kernel(const float* __restrict__ h2g, const int* __restrict__ lens,
             const float* __restrict__ lw1, const float* __restrict__ lb1,
             const float* __restrict__ lw2, const float* __restrict__ lb2,
             const float* __restrict__ outc, float* __restrict__ out) {
  const int tid = threadIdx.x;
  const int wid = tid >> 6, lane = tid & 63;
  const int jj = (lane < HID) ? lane : (HID - 1);
  const int l1 = (lane < 50) ? lane : 49;  // this lane's vocab cols: l1, l1+50

  float w1x[15], w1y[15];  // lw1 row jj, pairs
#pragma unroll
  for (int p = 0; p < 15; ++p) {
    w1x[p] = lw1[jj * HID + 2 * p];
    w1y[p] = lw1[jj * HID + 2 * p + 1];
  }
  float w2a[HID], w2b[HID];  // lw2 rows l1, l1+50
#pragma unroll
  for (int k = 0; k < HID; ++k) {
    w2a[k] = lw2[l1 * HID + k];
    w2b[k] = lw2[(l1 + 50) * HID + k];
  }
  const float lb1v = lb1[jj];
  const float lb2a = lb2[l1], lb2b = lb2[l1 + 50];
  const float oca = outc[l1], ocb = outc[l1 + 50];

  const int wgid = blockIdx.x * 4 + wid;
  const int r0 = wgid * 64;
  const int bb = r0 >> 9;  // constant for the whole wave
  const int t0 = r0 & (NT - 1);
  const int len = lens[bb];

#define LOAD_ROW(dst, tt_)                                                     \
  {                                                                            \
    const float2* hp = (const float2*)(h2g + ((size_t)((tt_)*NB + bb)) * HID); \
    _Pragma("unroll") for (int p = 0; p < 15; ++p) dst[p] = hp[p];             \
  }

#define PROC_ROW(hb, tt_)                                                   \
  {                                                                         \
    float* orow = out + ((size_t)(bb * NT + (tt_))) * VOCABN;               \
    if ((tt_) >= len) {                                                     \
      if (lane < 50) {                                                      \
        orow[l1] = oca;                                                     \
        orow[l1 + 50] = ocb;                                                \
      }                                                                     \
    } else {                                                                \
      float ma = lb1v, mb = 0.f;                                            \
      _Pragma("unroll") for (int p = 0; p < 15; ++p) {                      \
        if (p < 8) {                                                        \
          ma = fmaf(hb[p].x, w1x[p], ma);                                   \
          ma = fmaf(hb[p].y, w1y[p], ma);                                   \
        } else {                                                            \
          mb = fmaf(hb[p].x, w1x[p], mb);                                   \
          mb = fmaf(hb[p].y, w1y[p], mb);                                   \
        }                                                                   \
      }                                                                     \
      float m = fmaxf(ma + mb, 0.f);                                        \
      float sm[HID];                                                        \
      _Pragma("unroll") for (int k = 0; k < HID; ++k) sm[k] = rdlane(m, k); \
      float oa0 = lb2a, oa1 = 0.f, ob0 = lb2b, ob1 = 0.f;                   \
      _Pragma("unroll") for (int k = 0; k < 15; ++k) {                      \
        oa0 = fmaf(sm[k], w2a[k], oa0);                                     \
        ob0 = fmaf(sm[k], w2b[k], ob0);                                     \
        oa1 = fmaf(sm[k + 15], w2a[k + 15], oa1);                           \
        ob1 = fmaf(sm[k + 15], w2b[k + 15], ob1);                           \
      }                                                                     \
      if (lane < 50) {                                                      \
        orow[l1] = oa0 + oa1;                                               \
        orow[l1 + 50] = ob0 + ob1;                                          \
      }                                                                     \
    }                                                                       \
  }

  float2 hA[15], hB[15];
  LOAD_ROW(hA, t0)
  for (int t = t0; t < t0 + 64; t += 2) {
    int tn1 = t + 1;
    LOAD_ROW(hB, tn1)
    PROC_ROW(hA, t)
    int tn2 = (t + 2 < NT) ? (t + 2) : (NT - 1);
    LOAD_ROW(hA, tn2)
    PROC_ROW(hB, tn1)
  }
#undef LOAD_ROW
#undef PROC_ROW
}

extern "C" void kernel_launch(void* const* d_in, const int* in_sizes, int n_in,
                              void* d_out, int out_size, void* d_ws, size_t ws_size,
                              hipStream_t stream) {
  const int* batch_x = (const int*)d_in[0];
  const int* lens = (const int*)d_in[1];
  const float* emb = (const float*)d_in[2];
  const float* w_ih1 = (const float*)d_in[3];
  const float* w_hh1 = (const float*)d_in[4];
  const float* b_ih1 = (const float*)d_in[5];
  const float* b_hh1 = (const float*)d_in[6];
  const float* w_ih2 = (const float*)d_in[7];
  const float* w_hh2 = (const float*)d_in[8];
  const float* b_ih2 = (const float*)d_in[9];
  const float* b_hh2 = (const float*)d_in[10];
  const float* lw1 = (const float*)d_in[11];
  const float* lb1 = (const float*)d_in[12];
  const float* lw2 = (const float*)d_in[13];
  const float* lb2 = (const float*)d_in[14];
  float* out = (float*)d_out;

  char* ws = (char*)d_ws;
  float* xpe = (float*)ws;                 // 100*120 floats
  float* b2s = (float*)(ws + 48 * 1024);   // 120 floats
  float* outc = (float*)(ws + 56 * 1024);  // 100 floats
  float* h2g = (float*)(ws + 64 * 1024);   // 512*512*30 floats (~31.5 MB)

  prep_kernel<<<VOCABN, 128, 0, stream>>>(emb, w_ih1, b_ih1, b_hh1, b_ih2, b_hh2,
                                          lw2, lb1, lb2, xpe, b2s, outc);
  scan_kernel<<<NB, 64, 0, stream>>>(batch_x, lens, xpe, b2s, w_hh1, w_ih2, w_hh2, h2g);
  final_kernel<<<(NB * NT) / 256, 256, 0, stream>>>(h2g, lens, lw1, lb1, lw2, lb2, outc, out);
}

// Round 11
// 343.149 us; speedup vs baseline: 1.5550x; 1.5550x over previous
//
#include <hip/hip_runtime.h>
#include <math.h>

#define VOCABN 100
#define EMBEDN 50
#define HID 30
#define NB 512
#define NT 512
#define G4 120   // 4*HID
#define RD 32    // ring depth (power of 2)

typedef float v2f __attribute__((ext_vector_type(2)));

__device__ __forceinline__ float fastrcp(float x) {
  float r;
  asm("v_rcp_f32 %0, %1" : "=v"(r) : "v"(x));
  return r;
}
__device__ __forceinline__ float tanh_fast(float x) {
  return 1.0f - 2.0f * fastrcp(1.0f + __expf(2.0f * x));
}
__device__ __forceinline__ v2f mk2(float a, float b) { v2f r; r[0] = a; r[1] = b; return r; }
// v_permlane32_swap(x,x): lo_all = lanes[0..31]'s value in all lanes, hi_all = lanes[32..63]'s.
__device__ __forceinline__ void bcast_halves(float x, float& lo_all, float& hi_all) {
  auto r = __builtin_amdgcn_permlane32_swap(__builtin_bit_cast(unsigned, x),
                                            __builtin_bit_cast(unsigned, x), false, false);
  lo_all = __builtin_bit_cast(float, (unsigned)r[0]);
  hi_all = __builtin_bit_cast(float, (unsigned)r[1]);
}
__device__ __forceinline__ float rdlane(float v, int k) {
  return __builtin_bit_cast(float, __builtin_amdgcn_readlane(__builtin_bit_cast(int, v), k));
}
__device__ __forceinline__ int flag_ld(const int* p) {
  return __hip_atomic_load(p, __ATOMIC_RELAXED, __HIP_MEMORY_SCOPE_WORKGROUP);
}
__device__ __forceinline__ void flag_st(int* p, int v) {
  __hip_atomic_store(p, v, __ATOMIC_RELAXED, __HIP_MEMORY_SCOPE_WORKGROUP);
}
// drain DS queue so a following flag store is ordered after prior LDS data writes
__device__ __forceinline__ void lds_fence() {
  asm volatile("s_waitcnt lgkmcnt(0)" ::: "memory");
}

// ---------------- prep: xpe[tok][g] = emb[tok]@w_ih1^T + b_ih1 + b_hh1 ; b2s = b_ih2+b_hh2
// also outc[v] = lb2[v] + relu(lb1) . lw2[v]  (output row for masked timesteps)
__global__ void prep_kernel(const float* __restrict__ emb,
                            const float* __restrict__ w_ih1,
                            const float* __restrict__ b_ih1,
                            const float* __restrict__ b_hh1,
                            const float* __restrict__ b_ih2,
                            const float* __restrict__ b_hh2,
                            const float* __restrict__ lw2,
                            const float* __restrict__ lb1,
                            const float* __restrict__ lb2,
                            float* __restrict__ xpe, float* __restrict__ b2s,
                            float* __restrict__ outc) {
  __shared__ float e[EMBEDN];
  int r = blockIdx.x;
  int tid = threadIdx.x;
  if (tid < EMBEDN) e[tid] = emb[r * EMBEDN + tid];
  __syncthreads();
  if (tid < G4) {
    float s = b_ih1[tid] + b_hh1[tid];
#pragma unroll
    for (int k = 0; k < EMBEDN; ++k) s = fmaf(e[k], w_ih1[tid * EMBEDN + k], s);
    xpe[r * G4 + tid] = s;
    if (r == 0) b2s[tid] = b_ih2[tid] + b_hh2[tid];
  }
  if (r == 0 && tid < VOCABN) {
    float o = lb2[tid];
#pragma unroll
    for (int k = 0; k < HID; ++k) o = fmaf(fmaxf(lb1[k], 0.f), lw2[tid * HID + k], o);
    outc[tid] = o;
  }
}

// ---------------- scan: 3 decoupled waves per sequence, NO in-loop barriers.
// Sound flag-first protocol: consumer spins on the flag counter BEFORE issuing
// data reads (per-wave in-order DS pipe => reads sample LDS after the flag was
// seen => after the producer's fenced writes). `avail` caching means one poll
// can cover many steps when the producer runs ahead.
//   W0: h1[t] (state in SGPRs)    -> h1ring, flag0
//   W1: u[t] = w_ih2 . h1[t]      -> uring,  flag1
//   W2: h2[t] (state in SGPRs)    -> h2g,    flag2 (progress only)
__global__ void __launch_bounds__(192) scan_kernel(
    const int* __restrict__ batch_x, const int* __restrict__ lens,
    const float* __restrict__ xpe, const float* __restrict__ b2s,
    const float* __restrict__ w_hh1, const float* __restrict__ w_ih2,
    const float* __restrict__ w_hh2, float* __restrict__ h2g) {
  __shared__ __align__(16) float h1ring[RD][32];
  __shared__ __align__(16) float2 uring[RD][64];
  __shared__ int tok_lds[NT];
  __shared__ int flags[4];

  const int b = blockIdx.x;
  const int tid = threadIdx.x;
  const int wid = tid >> 6;  // 0,1,2
  const int lane = tid & 63;
  const int half = lane >> 5;
  const int j = lane & 31;
  const int jj = (j < HID) ? j : (HID - 1);
  // half0 lane j: gates (i_j, f_j); half1 lane j: gates (g_j, o_j)
  const int gA = half ? (jj + 2 * HID) : jj;
  const int gB = half ? (jj + 3 * HID) : (jj + HID);
  const float bg = half ? 2.0f : 1.0f;  // beta: 1 -> sigmoid, 2 -> tanh

  const int* xrow = batch_x + b * NT;
  for (int i = tid; i < NT; i += 192) tok_lds[i] = xrow[i];
  if (tid < 4) flags[tid] = 0;

  // per-wave weight slice: rows gA,gB of this wave's matrix (60 VGPR)
  const float* wsrc = (wid == 0) ? w_hh1 : (wid == 1) ? w_ih2 : w_hh2;
  float wA[HID], wB[HID];
#pragma unroll
  for (int k = 0; k < HID; ++k) {
    wA[k] = wsrc[gA * HID + k];
    wB[k] = wsrc[gB * HID + k];
  }
  const float b2A = b2s[gA], b2B = b2s[gB];
  const int len = lens[b];
  __syncthreads();  // staging + flag init; ONLY barrier in the kernel

  if (wid == 0) {
    // ---------------- W0: layer-1 recurrence, state in SGPRs
    float c1 = 0.f;
    float hs1[HID];
    {
      int tok0 = tok_lds[0];
      float a0 = xpe[tok0 * G4 + gA];
      float a1 = xpe[tok0 * G4 + gB];
      float sA = 1.0f - bg * fastrcp(1.0f + __expf(bg * a0));
      float sB = 1.0f - fastrcp(1.0f + __expf(a1));
      float i1, g1, f1, o1;
      bcast_halves(sA, i1, g1);
      bcast_halves(sB, f1, o1);
      (void)f1;
      c1 = i1 * g1;
      float h1n = o1 * tanh_fast(c1);
      if (lane < 32) h1ring[0][j] = h1n;
      lds_fence();
      if (lane == 0) flag_st(&flags[0], 1);
#pragma unroll
      for (int k = 0; k < HID; ++k) hs1[k] = rdlane(h1n, k);
    }
    int tk = tok_lds[1];
    float xaC = xpe[tk * G4 + gA], xbC = xpe[tk * G4 + gB];
    tk = tok_lds[2 < NT ? 2 : NT - 1];
    float xaN = xpe[tk * G4 + gA], xbN = xpe[tk * G4 + gB];

    for (int t = 1; t < len; ++t) {
      if ((t & 7) == 0) {  // backpressure: lead over W1 stays < 24 (< RD)
        int f1s = flag_ld(&flags[1]);
        while (f1s < t - 16) f1s = flag_ld(&flags[1]);
      }
      float a0a = 0.f, a0b = 0.f, a1a = 0.f, a1b = 0.f;
#pragma unroll
      for (int p = 0; p < 15; ++p) {
        a0a = fmaf(hs1[p], wA[p], a0a);
        a1a = fmaf(hs1[p], wB[p], a1a);
        a0b = fmaf(hs1[p + 15], wA[p + 15], a0b);
        a1b = fmaf(hs1[p + 15], wB[p + 15], a1b);
      }
      float a0 = a0a + a0b + xaC;
      float a1 = a1a + a1b + xbC;
      float sA = 1.0f - bg * fastrcp(1.0f + __expf(bg * a0));
      float sB = 1.0f - fastrcp(1.0f + __expf(a1));
      float i1, g1, f1, o1;
      bcast_halves(sA, i1, g1);
      bcast_halves(sB, f1, o1);
      c1 = fmaf(f1, c1, i1 * g1);
      float h1n = o1 * tanh_fast(c1);
      if (lane < 32) h1ring[t & (RD - 1)][j] = h1n;
      lds_fence();  // only the ring write outstanding here
      if (lane == 0) flag_st(&flags[0], t + 1);
#pragma unroll
      for (int k = 0; k < HID; ++k) hs1[k] = rdlane(h1n, k);
      // prefetch AFTER fence so lgkmcnt(0) never waits on these
      xaC = xaN;
      xbC = xbN;
      int tn = t + 2;
      tk = tok_lds[(tn < NT) ? tn : (NT - 1)];
      xaN = xpe[tk * G4 + gA];
      xbN = xpe[tk * G4 + gB];
    }
  } else if (wid == 1) {
    // ---------------- W1: u[t] = w_ih2 . h1[t]
    int avail = 0;
    for (int t = 0; t < len; ++t) {
      if ((t & 7) == 0) {  // backpressure vs W2
        int f2s = flag_ld(&flags[2]);
        while (f2s < t - 16) f2s = flag_ld(&flags[2]);
      }
      if (avail <= t) {
        do { avail = flag_ld(&flags[0]); } while (avail <= t);
      }
      // data reads issue after the flag branch -> sound (in-order DS pipe)
      const float2* hp = (const float2*)h1ring[t & (RD - 1)];
      float2 hv[15];
#pragma unroll
      for (int p = 0; p < 15; ++p) hv[p] = hp[p];
      float q0a = 0.f, q0b = 0.f, q1a = 0.f, q1b = 0.f;
#pragma unroll
      for (int p = 0; p < 15; ++p) {
        if (p < 8) {
          q0a = fmaf(hv[p].x, wA[2 * p], q0a);
          q1a = fmaf(hv[p].x, wB[2 * p], q1a);
          q0a = fmaf(hv[p].y, wA[2 * p + 1], q0a);
          q1a = fmaf(hv[p].y, wB[2 * p + 1], q1a);
        } else {
          q0b = fmaf(hv[p].x, wA[2 * p], q0b);
          q1b = fmaf(hv[p].x, wB[2 * p], q1b);
          q0b = fmaf(hv[p].y, wA[2 * p + 1], q0b);
          q1b = fmaf(hv[p].y, wB[2 * p + 1], q1b);
        }
      }
      float2 u;
      u.x = q0a + q0b;
      u.y = q1a + q1b;
      uring[t & (RD - 1)][lane] = u;
      lds_fence();
      if (lane == 0) flag_st(&flags[1], t + 1);
    }
  } else {
    // ---------------- W2: layer-2 recurrence, state in SGPRs, + store
    float c2 = 0.f;
    float hs2[HID];
#pragma unroll
    for (int k = 0; k < HID; ++k) hs2[k] = 0.f;
    int avail = 0;
    for (int t = 0; t < len; ++t) {
      if (avail <= t) {
        do { avail = flag_ld(&flags[1]); } while (avail <= t);
      }
      float2 u = uring[t & (RD - 1)][lane];  // after flag branch -> valid
      float q0a = 0.f, q0b = 0.f, q1a = 0.f, q1b = 0.f;
#pragma unroll
      for (int p = 0; p < 15; ++p) {
        q0a = fmaf(hs2[p], wA[p], q0a);
        q1a = fmaf(hs2[p], wB[p], q1a);
        q0b = fmaf(hs2[p + 15], wA[p + 15], q0b);
        q1b = fmaf(hs2[p + 15], wB[p + 15], q1b);
      }
      float q0 = q0a + q0b + u.x + b2A;
      float q1 = q1a + q1b + u.y + b2B;
      float uA = 1.0f - bg * fastrcp(1.0f + __expf(bg * q0));
      float uB = 1.0f - fastrcp(1.0f + __expf(q1));
      float i2, g2, f2, o2;
      bcast_halves(uA, i2, g2);
      bcast_halves(uB, f2, o2);
      c2 = fmaf(f2, c2, i2 * g2);
      float h2n = o2 * tanh_fast(c2);
      if (lane < HID) h2g[((size_t)t * NB + b) * HID + lane] = h2n;  // async store
      lds_fence();  // uring read definitely complete before signaling consumption
      if (lane == 0) flag_st(&flags[2], t + 1);
#pragma unroll
      for (int k = 0; k < HID; ++k) hs2[k] = rdlane(h2n, k);
    }
  }
}

// ---------------- head MLP: no LDS. Per-lane hoisted weights; hmid broadcast
// via readlane->SGPR; next-row global prefetch; 2-row ping-pong.
__global__ void __launch_bounds__(256)
__attribute__((amdgpu_waves_per_eu(1, 2)))
final_kernel(const float* __restrict__ h2g, const int* __restrict__ lens,
             const float* __restrict__ lw1, const float* __restrict__ lb1,
             const float* __restrict__ lw2, const float* __restrict__ lb2,
             const float* __restrict__ outc, float* __restrict__ out) {
  const int tid = threadIdx.x;
  const int wid = tid >> 6, lane = tid & 63;
  const int jj = (lane < HID) ? lane : (HID - 1);
  const int l1 = (lane < 50) ? lane : 49;  // this lane's vocab cols: l1, l1+50

  float w1x[15], w1y[15];
#pragma unroll
  for (int p = 0; p < 15; ++p) {
    w1x[p] = lw1[jj * HID + 2 * p];
    w1y[p] = lw1[jj * HID + 2 * p + 1];
  }
  float w2a[HID], w2b[HID];
#pragma unroll
  for (int k = 0; k < HID; ++k) {
    w2a[k] = lw2[l1 * HID + k];
    w2b[k] = lw2[(l1 + 50) * HID + k];
  }
  const float lb1v = lb1[jj];
  const float lb2a = lb2[l1], lb2b = lb2[l1 + 50];
  const float oca = outc[l1], ocb = outc[l1 + 50];

  const int wgid = blockIdx.x * 4 + wid;
  const int r0 = wgid * 64;
  const int bb = r0 >> 9;
  const int t0 = r0 & (NT - 1);
  const int len = lens[bb];

#define LOAD_ROW(dst, tt_)                                                     \
  {                                                                            \
    const float2* hp = (const float2*)(h2g + ((size_t)((tt_)*NB + bb)) * HID); \
    _Pragma("unroll") for (int p = 0; p < 15; ++p) dst[p] = hp[p];             \
  }

#define PROC_ROW(hb, tt_)                                                   \
  {                                                                         \
    float* orow = out + ((size_t)(bb * NT + (tt_))) * VOCABN;               \
    if ((tt_) >= len) {                                                     \
      if (lane < 50) {                                                      \
        orow[l1] = oca;                                                     \
        orow[l1 + 50] = ocb;                                                \
      }                                                                     \
    } else {                                                                \
      float ma = lb1v, mb = 0.f;                                            \
      _Pragma("unroll") for (int p = 0; p < 15; ++p) {                      \
        if (p < 8) {                                                        \
          ma = fmaf(hb[p].x, w1x[p], ma);                                   \
          ma = fmaf(hb[p].y, w1y[p], ma);                                   \
        } else {                                                            \
          mb = fmaf(hb[p].x, w1x[p], mb);                                   \
          mb = fmaf(hb[p].y, w1y[p], mb);                                   \
        }                                                                   \
      }                                                                     \
      float m = fmaxf(ma + mb, 0.f);                                        \
      float sm[HID];                                                        \
      _Pragma("unroll") for (int k = 0; k < HID; ++k) sm[k] = rdlane(m, k); \
      float oa0 = lb2a, oa1 = 0.f, ob0 = lb2b, ob1 = 0.f;                   \
      _Pragma("unroll") for (int k = 0; k < 15; ++k) {                      \
        oa0 = fmaf(sm[k], w2a[k], oa0);                                     \
        ob0 = fmaf(sm[k], w2b[k], ob0);                                     \
        oa1 = fmaf(sm[k + 15], w2a[k + 15], oa1);                           \
        ob1 = fmaf(sm[k + 15], w2b[k + 15], ob1);                           \
      }                                                                     \
      if (lane < 50) {                                                      \
        orow[l1] = oa0 + oa1;                                               \
        orow[l1 + 50] = ob0 + ob1;                                          \
      }                                                                     \
    }                                                                       \
  }

  float2 hA[15], hB[15];
  LOAD_ROW(hA, t0)
  for (int t = t0; t < t0 + 64; t += 2) {
    int tn1 = t + 1;
    LOAD_ROW(hB, tn1)
    PROC_ROW(hA, t)
    int tn2 = (t + 2 < NT) ? (t + 2) : (NT - 1);
    LOAD_ROW(hA, tn2)
    PROC_ROW(hB, tn1)
  }
#undef LOAD_ROW
#undef PROC_ROW
}

extern "C" void kernel_launch(void* const* d_in, const int* in_sizes, int n_in,
                              void* d_out, int out_size, void* d_ws, size_t ws_size,
                              hipStream_t stream) {
  const int* batch_x = (const int*)d_in[0];
  const int* lens = (const int*)d_in[1];
  const float* emb = (const float*)d_in[2];
  const float* w_ih1 = (const float*)d_in[3];
  const float* w_hh1 = (const float*)d_in[4];
  const float* b_ih1 = (const float*)d_in[5];
  const float* b_hh1 = (const float*)d_in[6];
  const float* w_ih2 = (const float*)d_in[7];
  const float* w_hh2 = (const float*)d_in[8];
  const float* b_ih2 = (const float*)d_in[9];
  const float* b_hh2 = (const float*)d_in[10];
  const float* lw1 = (const float*)d_in[11];
  const float* lb1 = (const float*)d_in[12];
  const float* lw2 = (const float*)d_in[13];
  const float* lb2 = (const float*)d_in[14];
  float* out = (float*)d_out;

  char* ws = (char*)d_ws;
  float* xpe = (float*)ws;                 // 100*120 floats
  float* b2s = (float*)(ws + 48 * 1024);   // 120 floats
  float* outc = (float*)(ws + 56 * 1024);  // 100 floats
  float* h2g = (float*)(ws + 64 * 1024);   // 512*512*30 floats (~31.5 MB)

  prep_kernel<<<VOCABN, 128, 0, stream>>>(emb, w_ih1, b_ih1, b_hh1, b_ih2, b_hh2,
                                          lw2, lb1, lb2, xpe, b2s, outc);
  scan_kernel<<<NB, 192, 0, stream>>>(batch_x, lens, xpe, b2s, w_hh1, w_ih2, w_hh2, h2g);
  final_kernel<<<(NB * NT) / 256, 256, 0, stream>>>(h2g, lens, lw1, lb1, lw2, lb2, outc, out);
}